// Round 3
// baseline (894.809 us; speedup 1.0000x reference)
//
#include <hip/hip_runtime.h>
#include <hip/hip_bf16.h>

// ---------------- workspace layout (bytes) ----------------
// total footprint: 2,703,360 bytes (~2.6 MB)
#define AGG_OFF     0u          // f32[4096*50]  (zeroed)
#define DEG_OFF     819200u     // f32[4096]     (zeroed)
#define XP_OFF      835584u     // f32[64]       (zeroed)
#define HIST_OFF    835840u     // u32[257]      (zeroed)
#define SCAL_OFF    836992u     // i32[8]        (zeroed; written by scan)
#define H_OFF       1048576u    // f32[4096][50] row-major
#define HT_OFF      1867776u    // f32[50][4096] transposed
#define SQ_OFF      2686976u    // f32[4096] row squared-norms

// ============================================================
// Kernel 0: zero the accumulator region of the workspace
// ============================================================
__global__ __launch_bounds__(256) void mil_init(unsigned int* __restrict__ w)
{
    w[(size_t)blockIdx.x * 256u + threadIdx.x] = 0u;
}

// ============================================================
// Kernel 1: per-instance LeNet: conv1+relu+pool, conv2+relu+pool,
// fc+relu -> h[4096][50], hT[50][4096], sq[4096]
// (bias added after maxpool: valid & bitwise-equal since f32 add is
//  monotone and bias is per-channel const; relu/max monotone)
// ============================================================
__global__ __launch_bounds__(256) void mil_cnn(
    const float* __restrict__ x, const float* __restrict__ w1, const float* __restrict__ b1,
    const float* __restrict__ w2, const float* __restrict__ b2,
    const float* __restrict__ fcw, const float* __restrict__ fcb,
    float* __restrict__ hout, float* __restrict__ hT, float* __restrict__ sqout)
{
    __shared__ __align__(16) float img[784];
    __shared__ float w1s[500];
    __shared__ float b1s[20];
    __shared__ float b2s[50];
    __shared__ __align__(16) float pool1[20*144];
    __shared__ float w2s[50*4*25];
    __shared__ __align__(16) float pool2[800];
    __shared__ float hloc[50];

    const int n = blockIdx.x;
    const int t = threadIdx.x;

    const float* xin = x + (size_t)n * 784;
    for (int i = t; i < 784; i += 256) img[i] = xin[i];
    for (int i = t; i < 500; i += 256) w1s[i] = w1[i];
    if (t < 20) b1s[t] = b1[t];
    { int u = t - 32; if (u >= 0 && u < 50) b2s[u] = b2[u]; }
    __syncthreads();

    // ---- conv1 (5x5, 1->20) + relu + 2x2 maxpool -> pool1[20][12][12]
    if (t < 240) {
        const int c = t / 12, py = t % 12;
        float wr[25];
#pragma unroll
        for (int k = 0; k < 25; k++) wr[k] = w1s[c*25 + k];
        float acc0[24], acc1[24];
#pragma unroll
        for (int i = 0; i < 24; i++) { acc0[i] = 0.f; acc1[i] = 0.f; }
#pragma unroll
        for (int ky = 0; ky < 5; ky++) {
            const int yr = 2*py + ky;
            float ra[28], rb[28];
#pragma unroll
            for (int i = 0; i < 28; i++) ra[i] = img[yr*28 + i];
#pragma unroll
            for (int i = 0; i < 28; i++) rb[i] = img[yr*28 + 28 + i];
#pragma unroll
            for (int kx = 0; kx < 5; kx++) {
                const float wv = wr[ky*5 + kx];
#pragma unroll
                for (int xo = 0; xo < 24; xo++) {
                    acc0[xo] = fmaf(ra[xo+kx], wv, acc0[xo]);
                    acc1[xo] = fmaf(rb[xo+kx], wv, acc1[xo]);
                }
            }
        }
        const float bias = b1s[c];
#pragma unroll
        for (int px = 0; px < 12; px++) {
            float v = fmaxf(fmaxf(acc0[2*px], acc0[2*px+1]),
                            fmaxf(acc1[2*px], acc1[2*px+1]));
            pool1[c*144 + py*12 + px] = fmaxf(v + bias, 0.f);
        }
    }
    __syncthreads();

    // ---- conv2 (5x5, 20->50) + relu + pool -> pool2[50*16]; ci in 5 chunks of 4
    float acc2[16];
#pragma unroll
    for (int i = 0; i < 16; i++) acc2[i] = 0.f;
    const int c2 = t / 4, py2 = t % 4;   // valid when t < 200
    for (int cig = 0; cig < 5; cig++) {
        __syncthreads();
        for (int idx = t; idx < 5000; idx += 256) {
            const int cc = idx / 100, rem = idx % 100;
            w2s[idx] = w2[cc*500 + cig*100 + rem];
        }
        __syncthreads();
        if (t < 200) {
#pragma unroll
            for (int cl = 0; cl < 4; cl++) {
                const int cig4 = cig*4 + cl;
#pragma unroll
                for (int ky = 0; ky < 5; ky++) {
                    const int r = 2*py2 + ky;
                    float ra[12], rb[12];
#pragma unroll
                    for (int i = 0; i < 12; i++) ra[i] = pool1[cig4*144 + r*12 + i];
#pragma unroll
                    for (int i = 0; i < 12; i++) rb[i] = pool1[cig4*144 + (r+1)*12 + i];
#pragma unroll
                    for (int kx = 0; kx < 5; kx++) {
                        const float wv = w2s[(c2*4 + cl)*25 + ky*5 + kx];
#pragma unroll
                        for (int xo = 0; xo < 8; xo++) {
                            acc2[xo]   = fmaf(ra[xo+kx], wv, acc2[xo]);
                            acc2[8+xo] = fmaf(rb[xo+kx], wv, acc2[8+xo]);
                        }
                    }
                }
            }
        }
    }
    __syncthreads();
    if (t < 200) {
        const float bias = b2s[c2];
#pragma unroll
        for (int px = 0; px < 4; px++) {
            float v = fmaxf(fmaxf(acc2[2*px], acc2[2*px+1]),
                            fmaxf(acc2[8+2*px], acc2[8+2*px+1]));
            pool2[c2*16 + py2*4 + px] = fmaxf(v + bias, 0.f);
        }
    }
    __syncthreads();

    // ---- fc: h[o] = relu(sum_k fcw[o][k]*pool2[k] + fcb[o]); one wave per o-slice
    {
        const int wv = t >> 6, lane = t & 63;
        for (int o = wv; o < 50; o += 4) {
            float acc = 0.f;
#pragma unroll
            for (int r = 0; r < 13; r++) {
                const int k = r*64 + lane;
                if (k < 800) acc = fmaf(fcw[o*800 + k], pool2[k], acc);
            }
#pragma unroll
            for (int off = 32; off > 0; off >>= 1) acc += __shfl_xor(acc, off);
            if (lane == 0) hloc[o] = fmaxf(acc + fcb[o], 0.f);
        }
    }
    __syncthreads();
    if (t < 50) {
        const float v = hloc[t];
        hout[(size_t)n*50 + t] = v;
        hT[(size_t)t*4096 + n] = v;
    }
    if (t < 64) {
        float s = (t < 50) ? hloc[t]*hloc[t] : 0.f;
#pragma unroll
        for (int off = 32; off > 0; off >>= 1) s += __shfl_xor(s, off);
        if (t == 0) sqout[n] = s;
    }
}

// ============================================================
// Kernel 2: pairwise distances -> cumulative-histogram buckets.
// bucket k = smallest candidate index with dist < 3.5+0.5k (256 = none).
// cands 3.5+0.5k are exactly representable in f32 -> exact compares.
// ============================================================
__global__ __launch_bounds__(256) void mil_hist(
    const float* __restrict__ hT, const float* __restrict__ sq,
    unsigned int* __restrict__ hist)
{
    __shared__ __align__(16) float hiT[3200];   // [50][64]
    __shared__ __align__(16) float hjT[3200];
    __shared__ float sqi[64], sqj[64];
    __shared__ unsigned int lh[257];

    const int bi = blockIdx.x, bj = blockIdx.y, t = threadIdx.x;
    const int i0 = bi*64, j0 = bj*64;

    for (int idx = t; idx < 3200; idx += 256) {
        const int c = idx >> 6, l = idx & 63;
        hiT[idx] = hT[(size_t)c*4096 + i0 + l];
        hjT[idx] = hT[(size_t)c*4096 + j0 + l];
    }
    if (t < 64) { sqi[t] = sq[i0 + t]; sqj[t] = sq[j0 + t]; }
    for (int idx = t; idx < 257; idx += 256) lh[idx] = 0;
    __syncthreads();

    const int ti = t >> 4, tj = t & 15;
    float acc[4][4];
#pragma unroll
    for (int a = 0; a < 4; a++)
#pragma unroll
        for (int b = 0; b < 4; b++) acc[a][b] = 0.f;

    for (int c = 0; c < 50; c++) {
        const float4 av = *(const float4*)&hiT[c*64 + ti*4];
        const float4 bv = *(const float4*)&hjT[c*64 + tj*4];
        const float aa[4] = {av.x, av.y, av.z, av.w};
        const float bb[4] = {bv.x, bv.y, bv.z, bv.w};
#pragma unroll
        for (int a = 0; a < 4; a++)
#pragma unroll
            for (int b = 0; b < 4; b++)
                acc[a][b] = fmaf(aa[a], bb[b], acc[a][b]);
    }

    unsigned int cnt0 = 0;
#pragma unroll
    for (int a = 0; a < 4; a++) {
#pragma unroll
        for (int b = 0; b < 4; b++) {
            const int i = i0 + ti*4 + a, j = j0 + tj*4 + b;
            if (i == j) continue;                       // diagonal excluded
            const float d2 = sqi[ti*4+a] + sqj[tj*4+b] - 2.f*acc[a][b];
            const float d = sqrtf(fmaxf(d2, 0.f));
            int k = (int)floorf((d - 3.5f)*2.f) + 1;
            k = k < 0 ? 0 : (k > 256 ? 256 : k);
            // exact f32 fixup against cand_k = 3.5 + 0.5k
            while (k > 0   && d <  3.5f + 0.5f*(float)(k-1)) k--;
            while (k < 256 && d >= 3.5f + 0.5f*(float)k)     k++;
            if (k == 0) cnt0++;
            else atomicAdd(&lh[k], 1u);
        }
    }
#pragma unroll
    for (int off = 32; off > 0; off >>= 1) cnt0 += __shfl_xor(cnt0, off);
    if ((t & 63) == 0 && cnt0) atomicAdd(&lh[0], cnt0);
    __syncthreads();
    for (int idx = t; idx < 257; idx += 256)
        if (lh[idx]) atomicAdd(&hist[idx], lh[idx]);
}

// ============================================================
// Kernel 3: prefix-scan histogram -> threshold index kc + edge count nnz
// (jnp.argmax of all-False = 0 -> fallback kc=0, matching reference)
// ============================================================
__global__ void mil_scan(const unsigned int* __restrict__ hist, int* __restrict__ scal)
{
    if (threadIdx.x == 0) {
        unsigned long long cum = 0, nz = 0;
        int kc = -1;
        for (int k = 0; k < 256; k++) {
            cum += hist[k];
            if (kc < 0 && cum >= 410ull) { kc = k; nz = cum; }  // ceil(0.1*4096)
        }
        if (kc < 0) { kc = 0; nz = hist[0]; }
        scal[0] = kc;
        scal[1] = (int)nz;
    }
}

// ============================================================
// Kernel 4: recompute distances (bitwise-identical FMA chain to mil_hist),
// mask with thr, aggregate: agg[i][d] += sum_{j in tile: edge} h[j][d]; deg[i].
// ============================================================
__global__ __launch_bounds__(256) void mil_agg(
    const float* __restrict__ h, const float* __restrict__ hT, const float* __restrict__ sq,
    const int* __restrict__ scal, float* __restrict__ agg, float* __restrict__ deg)
{
    __shared__ __align__(16) float hiT[3200];       // [50][64]
    __shared__ __align__(16) float hjT[3200];
    __shared__ float sqi[64], sqj[64];
    __shared__ __align__(16) float hsub[4096];      // [jj][d], d padded to 64
    __shared__ __align__(16) unsigned char mk[4096];// mask, transposed: [jj][il]

    const int t = threadIdx.x;
    const int i0 = blockIdx.x * 64;
    const float thr = 3.5f + 0.5f * (float)scal[0]; // exact in f32

    for (int idx = t; idx < 3200; idx += 256) {
        const int c = idx >> 6, l = idx & 63;
        hiT[idx] = hT[(size_t)c*4096 + i0 + l];
    }
    if (t < 64) sqi[t] = sq[i0 + t];

    const int ti = t >> 4, tj = t & 15;   // gram layout
    const int il = t >> 2, dq = t & 3;    // aggregate layout
    float accum[16];
#pragma unroll
    for (int i = 0; i < 16; i++) accum[i] = 0.f;
    int degc = 0;

    for (int js = 0; js < 8; js++) {
        const int j0 = blockIdx.y * 512 + js * 64;
        __syncthreads();
        for (int idx = t; idx < 3200; idx += 256) {
            const int c = idx >> 6, l = idx & 63;
            hjT[idx] = hT[(size_t)c*4096 + j0 + l];
        }
        for (int idx = t; idx < 4096; idx += 256) {
            const int jj = idx >> 6, d = idx & 63;
            hsub[idx] = (d < 50) ? h[(size_t)(j0 + jj)*50 + d] : 0.f;
        }
        if (t < 64) sqj[t] = sq[j0 + t];
        __syncthreads();

        // gram — identical op order to mil_hist
        float acc[4][4];
#pragma unroll
        for (int a = 0; a < 4; a++)
#pragma unroll
            for (int b = 0; b < 4; b++) acc[a][b] = 0.f;
        for (int c = 0; c < 50; c++) {
            const float4 av = *(const float4*)&hiT[c*64 + ti*4];
            const float4 bv = *(const float4*)&hjT[c*64 + tj*4];
            const float aa[4] = {av.x, av.y, av.z, av.w};
            const float bb[4] = {bv.x, bv.y, bv.z, bv.w};
#pragma unroll
            for (int a = 0; a < 4; a++)
#pragma unroll
                for (int b = 0; b < 4; b++)
                    acc[a][b] = fmaf(aa[a], bb[b], acc[a][b]);
        }

        // edge mask -> mk[jj][il] (transposed so aggregate reads broadcast)
#pragma unroll
        for (int b = 0; b < 4; b++) {
            unsigned char ob[4];
#pragma unroll
            for (int a = 0; a < 4; a++) {
                const int gi = i0 + ti*4 + a, gj = j0 + tj*4 + b;
                const float d2 = sqi[ti*4+a] + sqj[tj*4+b] - 2.f*acc[a][b];
                const float dd = sqrtf(fmaxf(d2, 0.f));
                ob[a] = (gi != gj && dd < thr) ? 1 : 0;
            }
            *(uchar4*)&mk[(tj*4+b)*64 + ti*4] = make_uchar4(ob[0], ob[1], ob[2], ob[3]);
        }
        __syncthreads();

        // masked accumulate: thread (il,dq) owns node i0+il, dims dq*16..dq*16+15
        for (int jj = 0; jj < 64; jj++) {
            const bool e = (mk[jj*64 + il] != 0);
            if (!__any(e)) continue;          // sparse-graph fast path
            const float m = e ? 1.f : 0.f;
            if (e && dq == 0) degc++;
#pragma unroll
            for (int q = 0; q < 4; q++) {
                const float4 hv = *(const float4*)&hsub[jj*64 + dq*16 + q*4];
                accum[q*4+0] = fmaf(m, hv.x, accum[q*4+0]);
                accum[q*4+1] = fmaf(m, hv.y, accum[q*4+1]);
                accum[q*4+2] = fmaf(m, hv.z, accum[q*4+2]);
                accum[q*4+3] = fmaf(m, hv.w, accum[q*4+3]);
            }
        }
    }

    const int node = i0 + il;
#pragma unroll
    for (int q = 0; q < 4; q++)
#pragma unroll
        for (int rr = 0; rr < 4; rr++) {
            const int d = dq*16 + q*4 + rr;
            if (d < 50 && accum[q*4+rr] != 0.f)
                atomicAdd(&agg[(size_t)node*50 + d], accum[q*4+rr]);
        }
    if (dq == 0 && degc) atomicAdd(&deg[node], (float)degc);
}

// ============================================================
// Kernel 5: Z = leaky(mean-agg@relW^T + relb + h@rootW^T); Xp += colsum(Z)
// ============================================================
__global__ __launch_bounds__(256) void mil_sage(
    const float* __restrict__ h, const float* __restrict__ agg, const float* __restrict__ deg,
    const float* __restrict__ relw, const float* __restrict__ relb,
    const float* __restrict__ rootw, float* __restrict__ Xp)
{
    __shared__ float relT[2500];   // [c][d]
    __shared__ float rootT[2500];
    __shared__ float rb[50];
    __shared__ float hn[250], mn[250], zb[250];
    const int t = threadIdx.x;
    const int nb = blockIdx.x * 5;

    for (int idx = t; idx < 2500; idx += 256) {
        const int d = idx / 50, c = idx % 50;
        relT[c*50 + d]  = relw[idx];
        rootT[c*50 + d] = rootw[idx];
    }
    if (t < 50) rb[t] = relb[t];
    if (t < 250) {
        const int nl = t / 50, d = t % 50;
        const int node = nb + nl;
        if (node < 4096) {
            hn[t] = h[(size_t)node*50 + d];
            mn[t] = agg[(size_t)node*50 + d] / fmaxf(deg[node], 1.f);
        } else { hn[t] = 0.f; mn[t] = 0.f; }
    }
    __syncthreads();
    if (t < 250) {
        const int nl = t / 50, d = t % 50;
        float z = rb[d];
        for (int c = 0; c < 50; c++) {
            z = fmaf(mn[nl*50 + c], relT[c*50 + d], z);
            z = fmaf(hn[nl*50 + c], rootT[c*50 + d], z);
        }
        z = z > 0.f ? z : 0.01f * z;
        zb[t] = (nb + nl < 4096) ? z : 0.f;
    }
    __syncthreads();
    if (t < 50) {
        float s = 0.f;
#pragma unroll
        for (int nl = 0; nl < 5; nl++) s += zb[nl*50 + t];
        atomicAdd(&Xp[t], s);
    }
}

// ============================================================
// Kernel 6: pooled sage + lin1 + lin2 + softmax -> out[3] (FLOAT32)
// S-branch is dead: softmax over length-1 axis == 1, so s = ones,
// Xp = colsum(Z), adjp = nnz, l1 = sqrt(N^2 - nnz)/N^2 (exact: A in {0,1}).
// ============================================================
__global__ void mil_final(
    const float* __restrict__ Xp, const int* __restrict__ scal,
    const float* __restrict__ relw, const float* __restrict__ relb,
    const float* __restrict__ rootw,
    const float* __restrict__ l1w, const float* __restrict__ l1b,
    const float* __restrict__ l2w, const float* __restrict__ l2b,
    float* __restrict__ out)
{
    __shared__ float xp[50], x2[50], v1[25], v2[2];
    const int t = threadIdx.x;
    if (t < 50) xp[t] = Xp[t];
    __syncthreads();
    const float adjp = (float)scal[1];
    const float dmax = fmaxf(adjp, 1.f);
    if (t < 50) {
        float z = relb[t];
        for (int c = 0; c < 50; c++) {
            // mimic ref rounding: (adjp*xp[c]) then /deg, two roundings
            const float mnc = (adjp * xp[c]) / dmax;
            z = fmaf(mnc,   relw[t*50 + c], z);
            z = fmaf(xp[c], rootw[t*50 + c], z);
        }
        x2[t] = z > 0.f ? z : 0.01f*z;
    }
    __syncthreads();
    if (t < 25) {
        float v = l1b[t];
        for (int c = 0; c < 50; c++) v = fmaf(l1w[t*50 + c], x2[c], v);
        v1[t] = v > 0.f ? v : 0.01f*v;
    }
    __syncthreads();
    if (t < 2) {
        float v = l2b[t];
        for (int c = 0; c < 25; c++) v = fmaf(l2w[t*25 + c], v1[c], v);
        v2[t] = v > 0.f ? v : 0.01f*v;
    }
    __syncthreads();
    if (t == 0) {
        const float a = v2[0], b = v2[1];
        const float mx = fmaxf(a, b);
        const float e0 = expf(a - mx), e1 = expf(b - mx);
        const float s = e0 + e1;
        const float p0 = e0 / s, p1 = e1 / s;
        const float pm = fmaxf(p0, p1);
        const float am = (p1 > p0) ? 1.f : 0.f;   // first-max tie-break (jnp.argmax)
        const int nnz = scal[1];
        const float l1v = sqrtf((float)(16777216 - nnz)) / 16777216.f;
        out[0] = pm;        // f32: reference output dtype is float32
        out[1] = am;
        out[2] = l1v;
    }
}

// ============================================================
extern "C" void kernel_launch(void* const* d_in, const int* in_sizes, int n_in,
                              void* d_out, int out_size, void* d_ws, size_t ws_size,
                              hipStream_t stream)
{
    (void)in_sizes; (void)n_in; (void)out_size; (void)ws_size;
    const float* x     = (const float*)d_in[0];
    const float* w1    = (const float*)d_in[1];
    const float* b1    = (const float*)d_in[2];
    const float* w2    = (const float*)d_in[3];
    const float* b2    = (const float*)d_in[4];
    const float* fcw   = (const float*)d_in[5];
    const float* fcb   = (const float*)d_in[6];
    const float* relw  = (const float*)d_in[7];
    const float* relb  = (const float*)d_in[8];
    const float* rootw = (const float*)d_in[9];
    // d_in[10..14] (pool_*, mlp_*) are dead: softmax over a length-1 axis == 1
    const float* l1w   = (const float*)d_in[15];
    const float* l1b   = (const float*)d_in[16];
    const float* l2w   = (const float*)d_in[17];
    const float* l2b   = (const float*)d_in[18];

    char* ws = (char*)d_ws;
    float* agg = (float*)(ws + AGG_OFF);
    float* deg = (float*)(ws + DEG_OFF);
    float* Xp  = (float*)(ws + XP_OFF);
    unsigned int* hist = (unsigned int*)(ws + HIST_OFF);
    int* scal  = (int*)(ws + SCAL_OFF);
    float* h   = (float*)(ws + H_OFF);
    float* hT  = (float*)(ws + HT_OFF);
    float* sq  = (float*)(ws + SQ_OFF);

    mil_init<<<818, 256, 0, stream>>>((unsigned int*)d_ws);
    mil_cnn<<<4096, 256, 0, stream>>>(x, w1, b1, w2, b2, fcw, fcb, h, hT, sq);
    mil_hist<<<dim3(64, 64), 256, 0, stream>>>(hT, sq, hist);
    mil_scan<<<1, 64, 0, stream>>>(hist, scal);
    mil_agg<<<dim3(64, 8), 256, 0, stream>>>(h, hT, sq, scal, agg, deg);
    mil_sage<<<820, 256, 0, stream>>>(h, agg, deg, relw, relb, rootw, Xp);
    mil_final<<<1, 64, 0, stream>>>(Xp, scal, relw, relb, rootw,
                                    l1w, l1b, l2w, l2b, (float*)d_out);
}

// Round 4
// 548.411 us; speedup vs baseline: 1.6316x; 1.6316x over previous
//
#include <hip/hip_runtime.h>
#include <hip/hip_bf16.h>

// ---------------- workspace layout (bytes) ----------------
#define AGG_OFF     0u          // f32[4096*50]  (zeroed)
#define DEG_OFF     819200u     // f32[4096]     (zeroed)
#define XP_OFF      835584u     // f32[64]       (zeroed)
#define HIST_OFF    835840u     // u32[257]      (zeroed)
#define SCAL_OFF    836992u     // i32[8]        (zeroed; written by scan)
#define S_OFF       837120u     // f32[50] colsum of h (written by colsum)
#define H_OFF       1048576u    // f32[4096][50] row-major
#define HT_OFF      1867776u    // f32[50][4096] transposed
#define SQ_OFF      2686976u    // f32[4096] row squared-norms

// ============================================================
// Kernel 0: zero the accumulator region of the workspace
// ============================================================
__global__ __launch_bounds__(256) void mil_init(unsigned int* __restrict__ w)
{
    w[(size_t)blockIdx.x * 256u + threadIdx.x] = 0u;
}

// ============================================================
// Kernel 1: per-instance LeNet -> h[4096][50], hT[50][4096], sq[4096]
// ============================================================
__global__ __launch_bounds__(256) void mil_cnn(
    const float* __restrict__ x, const float* __restrict__ w1, const float* __restrict__ b1,
    const float* __restrict__ w2, const float* __restrict__ b2,
    const float* __restrict__ fcw, const float* __restrict__ fcb,
    float* __restrict__ hout, float* __restrict__ hT, float* __restrict__ sqout)
{
    __shared__ __align__(16) float img[784];
    __shared__ float w1s[500];
    __shared__ float b1s[20];
    __shared__ float b2s[50];
    __shared__ __align__(16) float pool1[20*144];
    __shared__ float w2s[50*4*25];
    __shared__ __align__(16) float pool2[800];
    __shared__ float hloc[50];

    const int n = blockIdx.x;
    const int t = threadIdx.x;

    const float* xin = x + (size_t)n * 784;
    for (int i = t; i < 784; i += 256) img[i] = xin[i];
    for (int i = t; i < 500; i += 256) w1s[i] = w1[i];
    if (t < 20) b1s[t] = b1[t];
    { int u = t - 32; if (u >= 0 && u < 50) b2s[u] = b2[u]; }
    __syncthreads();

    // ---- conv1 (5x5, 1->20) + relu + 2x2 maxpool -> pool1[20][12][12]
    if (t < 240) {
        const int c = t / 12, py = t % 12;
        float wr[25];
#pragma unroll
        for (int k = 0; k < 25; k++) wr[k] = w1s[c*25 + k];
        float acc0[24], acc1[24];
#pragma unroll
        for (int i = 0; i < 24; i++) { acc0[i] = 0.f; acc1[i] = 0.f; }
#pragma unroll
        for (int ky = 0; ky < 5; ky++) {
            const int yr = 2*py + ky;
            float ra[28], rb[28];
#pragma unroll
            for (int i = 0; i < 28; i++) ra[i] = img[yr*28 + i];
#pragma unroll
            for (int i = 0; i < 28; i++) rb[i] = img[yr*28 + 28 + i];
#pragma unroll
            for (int kx = 0; kx < 5; kx++) {
                const float wv = wr[ky*5 + kx];
#pragma unroll
                for (int xo = 0; xo < 24; xo++) {
                    acc0[xo] = fmaf(ra[xo+kx], wv, acc0[xo]);
                    acc1[xo] = fmaf(rb[xo+kx], wv, acc1[xo]);
                }
            }
        }
        const float bias = b1s[c];
#pragma unroll
        for (int px = 0; px < 12; px++) {
            float v = fmaxf(fmaxf(acc0[2*px], acc0[2*px+1]),
                            fmaxf(acc1[2*px], acc1[2*px+1]));
            pool1[c*144 + py*12 + px] = fmaxf(v + bias, 0.f);
        }
    }
    __syncthreads();

    // ---- conv2 (5x5, 20->50) + relu + pool -> pool2[50*16]; ci in 5 chunks of 4
    float acc2[16];
#pragma unroll
    for (int i = 0; i < 16; i++) acc2[i] = 0.f;
    const int c2 = t / 4, py2 = t % 4;   // valid when t < 200
    for (int cig = 0; cig < 5; cig++) {
        __syncthreads();
        for (int idx = t; idx < 5000; idx += 256) {
            const int cc = idx / 100, rem = idx % 100;
            w2s[idx] = w2[cc*500 + cig*100 + rem];
        }
        __syncthreads();
        if (t < 200) {
#pragma unroll
            for (int cl = 0; cl < 4; cl++) {
                const int cig4 = cig*4 + cl;
#pragma unroll
                for (int ky = 0; ky < 5; ky++) {
                    const int r = 2*py2 + ky;
                    float ra[12], rb[12];
#pragma unroll
                    for (int i = 0; i < 12; i++) ra[i] = pool1[cig4*144 + r*12 + i];
#pragma unroll
                    for (int i = 0; i < 12; i++) rb[i] = pool1[cig4*144 + (r+1)*12 + i];
#pragma unroll
                    for (int kx = 0; kx < 5; kx++) {
                        const float wv = w2s[(c2*4 + cl)*25 + ky*5 + kx];
#pragma unroll
                        for (int xo = 0; xo < 8; xo++) {
                            acc2[xo]   = fmaf(ra[xo+kx], wv, acc2[xo]);
                            acc2[8+xo] = fmaf(rb[xo+kx], wv, acc2[8+xo]);
                        }
                    }
                }
            }
        }
    }
    __syncthreads();
    if (t < 200) {
        const float bias = b2s[c2];
#pragma unroll
        for (int px = 0; px < 4; px++) {
            float v = fmaxf(fmaxf(acc2[2*px], acc2[2*px+1]),
                            fmaxf(acc2[8+2*px], acc2[8+2*px+1]));
            pool2[c2*16 + py2*4 + px] = fmaxf(v + bias, 0.f);
        }
    }
    __syncthreads();

    // ---- fc: one wave per o-slice
    {
        const int wv = t >> 6, lane = t & 63;
        for (int o = wv; o < 50; o += 4) {
            float acc = 0.f;
#pragma unroll
            for (int r = 0; r < 13; r++) {
                const int k = r*64 + lane;
                if (k < 800) acc = fmaf(fcw[o*800 + k], pool2[k], acc);
            }
#pragma unroll
            for (int off = 32; off > 0; off >>= 1) acc += __shfl_xor(acc, off);
            if (lane == 0) hloc[o] = fmaxf(acc + fcb[o], 0.f);
        }
    }
    __syncthreads();
    if (t < 50) {
        const float v = hloc[t];
        hout[(size_t)n*50 + t] = v;
        hT[(size_t)t*4096 + n] = v;
    }
    if (t < 64) {
        float s = (t < 50) ? hloc[t]*hloc[t] : 0.f;
#pragma unroll
        for (int off = 32; off > 0; off >>= 1) s += __shfl_xor(s, off);
        if (t == 0) sqout[n] = s;
    }
}

// ============================================================
// Kernel 1b: S[d] = sum_n h[n][d]  (reads hT rows, coalesced)
// ============================================================
__global__ __launch_bounds__(256) void mil_colsum(
    const float* __restrict__ hT, float* __restrict__ S)
{
    __shared__ float red[4];
    const int d = blockIdx.x, t = threadIdx.x;
    float s = 0.f;
    for (int nn = t; nn < 4096; nn += 256) s += hT[(size_t)d*4096 + nn];
#pragma unroll
    for (int off = 32; off > 0; off >>= 1) s += __shfl_xor(s, off);
    if ((t & 63) == 0) red[t >> 6] = s;
    __syncthreads();
    if (t == 0) S[d] = red[0] + red[1] + red[2] + red[3];
}

// ============================================================
// Kernel 2: pairwise distances -> cumulative-histogram buckets.
// 128x128 tile / block, 8x8 per thread. Branchless exact bucket:
// k0 = floor((d-3.5)*2)+1 is within +-1 of true k*; one dec-then-inc
// with exact f32 candidate compares lands exactly on k*.
// ============================================================
__global__ __launch_bounds__(256, 3) void mil_hist(
    const float* __restrict__ hT, const float* __restrict__ sq,
    unsigned int* __restrict__ hist)
{
    __shared__ __align__(16) float hiT[6400];   // [50][128]
    __shared__ __align__(16) float hjT[6400];
    __shared__ float sqi[128], sqj[128];
    __shared__ unsigned int lh[257];

    const int t = threadIdx.x;
    const int i0 = blockIdx.x * 128, j0 = blockIdx.y * 128;

    for (int idx = t; idx < 6400; idx += 256) {
        const int c = idx >> 7, l = idx & 127;
        hiT[idx] = hT[(size_t)c*4096 + i0 + l];
        hjT[idx] = hT[(size_t)c*4096 + j0 + l];
    }
    if (t < 128) { sqi[t] = sq[i0 + t]; sqj[t] = sq[j0 + t]; }
    for (int idx = t; idx < 257; idx += 256) lh[idx] = 0;
    __syncthreads();

    const int ti = t >> 4, tj = t & 15;
    float acc[8][8];
#pragma unroll
    for (int a = 0; a < 8; a++)
#pragma unroll
        for (int b = 0; b < 8; b++) acc[a][b] = 0.f;

    for (int c = 0; c < 50; c++) {
        const float4 a0 = *(const float4*)&hiT[c*128 + ti*8];
        const float4 a1 = *(const float4*)&hiT[c*128 + ti*8 + 4];
        const float4 b0 = *(const float4*)&hjT[c*128 + tj*8];
        const float4 b1 = *(const float4*)&hjT[c*128 + tj*8 + 4];
        const float aa[8] = {a0.x,a0.y,a0.z,a0.w,a1.x,a1.y,a1.z,a1.w};
        const float bb[8] = {b0.x,b0.y,b0.z,b0.w,b1.x,b1.y,b1.z,b1.w};
#pragma unroll
        for (int a = 0; a < 8; a++)
#pragma unroll
            for (int b = 0; b < 8; b++)
                acc[a][b] = fmaf(aa[a], bb[b], acc[a][b]);
    }

    unsigned int cnt0 = 0;
#pragma unroll
    for (int a = 0; a < 8; a++) {
#pragma unroll
        for (int b = 0; b < 8; b++) {
            const int gi = i0 + ti*8 + a, gj = j0 + tj*8 + b;
            if (gi == gj) continue;                  // diagonal excluded
            const float d2 = sqi[ti*8+a] + sqj[tj*8+b] - 2.f*acc[a][b];
            const float d = sqrtf(fmaxf(d2, 0.f));
            int k = (int)floorf((d - 3.5f)*2.f) + 1;
            k = k < 0 ? 0 : (k > 256 ? 256 : k);
            if (k > 0   && d <  3.5f + 0.5f*(float)(k-1)) k--;
            if (k < 256 && d >= 3.5f + 0.5f*(float)k)     k++;
            if (k == 0) cnt0++;
            else atomicAdd(&lh[k], 1u);
        }
    }
#pragma unroll
    for (int off = 32; off > 0; off >>= 1) cnt0 += __shfl_xor(cnt0, off);
    if ((t & 63) == 0 && cnt0) atomicAdd(&lh[0], cnt0);
    __syncthreads();
    for (int idx = t; idx < 257; idx += 256)
        if (lh[idx]) atomicAdd(&hist[idx], lh[idx]);
}

// ============================================================
// Kernel 3: prefix-scan histogram -> kc, nnz, and complement flag
// ============================================================
__global__ void mil_scan(const unsigned int* __restrict__ hist, int* __restrict__ scal)
{
    if (threadIdx.x == 0) {
        unsigned long long cum = 0, nz = 0;
        int kc = -1;
        for (int k = 0; k < 256; k++) {
            cum += hist[k];
            if (kc < 0 && cum >= 410ull) { kc = k; nz = cum; }  // ceil(0.1*4096)
        }
        if (kc < 0) { kc = 0; nz = hist[0]; }
        scal[0] = kc;
        scal[1] = (int)nz;
        // complement mode when graph is more than half dense
        scal[2] = (nz * 2ull > 16773120ull) ? 1 : 0;   // 4096*4095 off-diag pairs
    }
}

// ============================================================
// Kernel 4: recompute distances (bitwise-identical FMA chain to mil_hist),
// accumulate mask (or complement mask when inv): agg/deg of the chosen set.
// ============================================================
__global__ __launch_bounds__(256, 3) void mil_agg(
    const float* __restrict__ h, const float* __restrict__ hT, const float* __restrict__ sq,
    const int* __restrict__ scal, float* __restrict__ agg, float* __restrict__ deg)
{
    __shared__ __align__(16) float hiT[3200];       // [50][64]
    __shared__ __align__(16) float hjT[3200];
    __shared__ float sqi[64], sqj[64];
    __shared__ __align__(16) float hsub[4096];      // [jj][d], d padded to 64
    __shared__ __align__(16) unsigned char mk[4096];// mask, transposed: [jj][il]

    const int t = threadIdx.x;
    const int i0 = blockIdx.x * 64;
    const float thr = 3.5f + 0.5f * (float)scal[0]; // exact in f32
    const bool inv = (scal[2] != 0);

    for (int idx = t; idx < 3200; idx += 256) {
        const int c = idx >> 6, l = idx & 63;
        hiT[idx] = hT[(size_t)c*4096 + i0 + l];
    }
    if (t < 64) sqi[t] = sq[i0 + t];

    const int ti = t >> 4, tj = t & 15;   // gram layout
    const int il = t >> 2, dq = t & 3;    // aggregate layout
    float accum[16];
#pragma unroll
    for (int i = 0; i < 16; i++) accum[i] = 0.f;
    int degc = 0;

    for (int js = 0; js < 8; js++) {
        const int j0 = blockIdx.y * 512 + js * 64;
        __syncthreads();
        for (int idx = t; idx < 3200; idx += 256) {
            const int c = idx >> 6, l = idx & 63;
            hjT[idx] = hT[(size_t)c*4096 + j0 + l];
        }
        for (int idx = t; idx < 4096; idx += 256) {
            const int jj = idx >> 6, d = idx & 63;
            hsub[idx] = (d < 50) ? h[(size_t)(j0 + jj)*50 + d] : 0.f;
        }
        if (t < 64) sqj[t] = sq[j0 + t];
        __syncthreads();

        // gram — identical per-pair op order to mil_hist
        float acc[4][4];
#pragma unroll
        for (int a = 0; a < 4; a++)
#pragma unroll
            for (int b = 0; b < 4; b++) acc[a][b] = 0.f;
        for (int c = 0; c < 50; c++) {
            const float4 av = *(const float4*)&hiT[c*64 + ti*4];
            const float4 bv = *(const float4*)&hjT[c*64 + tj*4];
            const float aa[4] = {av.x, av.y, av.z, av.w};
            const float bb[4] = {bv.x, bv.y, bv.z, bv.w};
#pragma unroll
            for (int a = 0; a < 4; a++)
#pragma unroll
                for (int b = 0; b < 4; b++)
                    acc[a][b] = fmaf(aa[a], bb[b], acc[a][b]);
        }

        // target-set mask -> mk[jj][il]  (edges, or non-edges when inv)
#pragma unroll
        for (int b = 0; b < 4; b++) {
            unsigned char ob[4];
#pragma unroll
            for (int a = 0; a < 4; a++) {
                const int gi = i0 + ti*4 + a, gj = j0 + tj*4 + b;
                const float d2 = sqi[ti*4+a] + sqj[tj*4+b] - 2.f*acc[a][b];
                const float dd = sqrtf(fmaxf(d2, 0.f));
                const bool edge = (dd < thr);
                ob[a] = (gi != gj && (edge != inv)) ? 1 : 0;
            }
            *(uchar4*)&mk[(tj*4+b)*64 + ti*4] = make_uchar4(ob[0], ob[1], ob[2], ob[3]);
        }
        __syncthreads();

        // masked accumulate: thread (il,dq) owns node i0+il, dims dq*16..+15
        for (int jj = 0; jj < 64; jj++) {
            const bool e = (mk[jj*64 + il] != 0);
            if (!__any(e)) continue;          // fast path: whole-wave skip
            const float m = e ? 1.f : 0.f;
            if (e && dq == 0) degc++;
#pragma unroll
            for (int q = 0; q < 4; q++) {
                const float4 hv = *(const float4*)&hsub[jj*64 + dq*16 + q*4];
                accum[q*4+0] = fmaf(m, hv.x, accum[q*4+0]);
                accum[q*4+1] = fmaf(m, hv.y, accum[q*4+1]);
                accum[q*4+2] = fmaf(m, hv.z, accum[q*4+2]);
                accum[q*4+3] = fmaf(m, hv.w, accum[q*4+3]);
            }
        }
    }

    const int node = i0 + il;
#pragma unroll
    for (int q = 0; q < 4; q++)
#pragma unroll
        for (int rr = 0; rr < 4; rr++) {
            const int d = dq*16 + q*4 + rr;
            if (d < 50 && accum[q*4+rr] != 0.f)
                atomicAdd(&agg[(size_t)node*50 + d], accum[q*4+rr]);
        }
    if (dq == 0 && degc) atomicAdd(&deg[node], (float)degc);
}

// ============================================================
// Kernel 5: Z = leaky(mean-agg@relW^T + relb + h@rootW^T); Xp += colsum(Z)
// Complement correction: agg_true = S - h[i] - comp; deg_true = 4095 - compdeg
// ============================================================
__global__ __launch_bounds__(256) void mil_sage(
    const float* __restrict__ h, const float* __restrict__ agg, const float* __restrict__ deg,
    const float* __restrict__ S, const int* __restrict__ scal,
    const float* __restrict__ relw, const float* __restrict__ relb,
    const float* __restrict__ rootw, float* __restrict__ Xp)
{
    __shared__ float relT[2500];   // [c][d]
    __shared__ float rootT[2500];
    __shared__ float rb[50];
    __shared__ float hn[250], mn[250], zb[250];
    const int t = threadIdx.x;
    const int nb = blockIdx.x * 5;
    const bool inv = (scal[2] != 0);

    for (int idx = t; idx < 2500; idx += 256) {
        const int d = idx / 50, c = idx % 50;
        relT[c*50 + d]  = relw[idx];
        rootT[c*50 + d] = rootw[idx];
    }
    if (t < 50) rb[t] = relb[t];
    if (t < 250) {
        const int nl = t / 50, d = t % 50;
        const int node = nb + nl;
        if (node < 4096) {
            const float hv = h[(size_t)node*50 + d];
            float av = agg[(size_t)node*50 + d];
            float dg = deg[node];
            if (inv) { av = S[d] - hv - av; dg = 4095.f - dg; }
            hn[t] = hv;
            mn[t] = av / fmaxf(dg, 1.f);
        } else { hn[t] = 0.f; mn[t] = 0.f; }
    }
    __syncthreads();
    if (t < 250) {
        const int nl = t / 50, d = t % 50;
        float z = rb[d];
        for (int c = 0; c < 50; c++) {
            z = fmaf(mn[nl*50 + c], relT[c*50 + d], z);
            z = fmaf(hn[nl*50 + c], rootT[c*50 + d], z);
        }
        z = z > 0.f ? z : 0.01f * z;
        zb[t] = (nb + nl < 4096) ? z : 0.f;
    }
    __syncthreads();
    if (t < 50) {
        float s = 0.f;
#pragma unroll
        for (int nl = 0; nl < 5; nl++) s += zb[nl*50 + t];
        atomicAdd(&Xp[t], s);
    }
}

// ============================================================
// Kernel 6: pooled sage + lin1 + lin2 + softmax -> out[3] (f32)
// ============================================================
__global__ void mil_final(
    const float* __restrict__ Xp, const int* __restrict__ scal,
    const float* __restrict__ relw, const float* __restrict__ relb,
    const float* __restrict__ rootw,
    const float* __restrict__ l1w, const float* __restrict__ l1b,
    const float* __restrict__ l2w, const float* __restrict__ l2b,
    float* __restrict__ out)
{
    __shared__ float xp[50], x2[50], v1[25], v2[2];
    const int t = threadIdx.x;
    if (t < 50) xp[t] = Xp[t];
    __syncthreads();
    const float adjp = (float)scal[1];
    const float dmax = fmaxf(adjp, 1.f);
    if (t < 50) {
        float z = relb[t];
        for (int c = 0; c < 50; c++) {
            const float mnc = (adjp * xp[c]) / dmax;
            z = fmaf(mnc,   relw[t*50 + c], z);
            z = fmaf(xp[c], rootw[t*50 + c], z);
        }
        x2[t] = z > 0.f ? z : 0.01f*z;
    }
    __syncthreads();
    if (t < 25) {
        float v = l1b[t];
        for (int c = 0; c < 50; c++) v = fmaf(l1w[t*50 + c], x2[c], v);
        v1[t] = v > 0.f ? v : 0.01f*v;
    }
    __syncthreads();
    if (t < 2) {
        float v = l2b[t];
        for (int c = 0; c < 25; c++) v = fmaf(l2w[t*25 + c], v1[c], v);
        v2[t] = v > 0.f ? v : 0.01f*v;
    }
    __syncthreads();
    if (t == 0) {
        const float a = v2[0], b = v2[1];
        const float mx = fmaxf(a, b);
        const float e0 = expf(a - mx), e1 = expf(b - mx);
        const float s = e0 + e1;
        const float p0 = e0 / s, p1 = e1 / s;
        const float pm = fmaxf(p0, p1);
        const float am = (p1 > p0) ? 1.f : 0.f;
        const int nnz = scal[1];
        const float l1v = sqrtf((float)(16777216 - nnz)) / 16777216.f;
        out[0] = pm;
        out[1] = am;
        out[2] = l1v;
    }
}

// ============================================================
extern "C" void kernel_launch(void* const* d_in, const int* in_sizes, int n_in,
                              void* d_out, int out_size, void* d_ws, size_t ws_size,
                              hipStream_t stream)
{
    (void)in_sizes; (void)n_in; (void)out_size; (void)ws_size;
    const float* x     = (const float*)d_in[0];
    const float* w1    = (const float*)d_in[1];
    const float* b1    = (const float*)d_in[2];
    const float* w2    = (const float*)d_in[3];
    const float* b2    = (const float*)d_in[4];
    const float* fcw   = (const float*)d_in[5];
    const float* fcb   = (const float*)d_in[6];
    const float* relw  = (const float*)d_in[7];
    const float* relb  = (const float*)d_in[8];
    const float* rootw = (const float*)d_in[9];
    // d_in[10..14] (pool_*, mlp_*) are dead: softmax over a length-1 axis == 1
    const float* l1w   = (const float*)d_in[15];
    const float* l1b   = (const float*)d_in[16];
    const float* l2w   = (const float*)d_in[17];
    const float* l2b   = (const float*)d_in[18];

    char* ws = (char*)d_ws;
    float* agg = (float*)(ws + AGG_OFF);
    float* deg = (float*)(ws + DEG_OFF);
    float* Xp  = (float*)(ws + XP_OFF);
    unsigned int* hist = (unsigned int*)(ws + HIST_OFF);
    int* scal  = (int*)(ws + SCAL_OFF);
    float* S   = (float*)(ws + S_OFF);
    float* h   = (float*)(ws + H_OFF);
    float* hT  = (float*)(ws + HT_OFF);
    float* sq  = (float*)(ws + SQ_OFF);

    mil_init<<<818, 256, 0, stream>>>((unsigned int*)d_ws);
    mil_cnn<<<4096, 256, 0, stream>>>(x, w1, b1, w2, b2, fcw, fcb, h, hT, sq);
    mil_colsum<<<50, 256, 0, stream>>>(hT, S);
    mil_hist<<<dim3(32, 32), 256, 0, stream>>>(hT, sq, hist);
    mil_scan<<<1, 64, 0, stream>>>(hist, scal);
    mil_agg<<<dim3(64, 8), 256, 0, stream>>>(h, hT, sq, scal, agg, deg);
    mil_sage<<<820, 256, 0, stream>>>(h, agg, deg, S, scal, relw, relb, rootw, Xp);
    mil_final<<<1, 64, 0, stream>>>(Xp, scal, relw, relb, rootw,
                                    l1w, l1b, l2w, l2b, (float*)d_out);
}